// Round 7
// baseline (379.920 us; speedup 1.0000x reference)
//
#include <hip/hip_runtime.h>

// ---------------------------------------------------------------------------
// HopfieldLayer via 3x MX-fp8 MFMA GEMMs (mfma_scale_f32_16x16x128_f8f6f4,
// uniform scales = 1.0). Softmax folded: GEMM2 stores F = 32*(exp(beta*l)-1)
// in fp8 + fp32 row sums; GEMM3 computes
// out = (colsum + F@xi/32) / (8192 + rowsum/32) with exact fp32 colsum.
// All K-orders carry the sigma permutation (within 128-chunks) consistently
// on both operands -> dot products are perm-invariant. (Validated in R10.)
//
// R11: ZERO-LDS GEMM. R10's closing decomposition: GEMM2 has only 8 K-iters;
// measured 2200 cy/block-iter vs ~550 MFMA + ~400 LDS work -> ~60% of every
// iteration is exposed latency + barrier skew, overlapped only across 2
// barrier-coupled blocks. All R5-R10 variants kept that structure and all
// landed 117-130us. Exit: EVERY matrix here is produced by our own kernels,
// so BOTH operands are pre-packed fragment-native (R10 proved the B-side
// mechanism + layout algebra):
//   pack[tile16][kt][quad][half][ln][16B]  == bpack_addr(row-or-col, s, kt)
// -> each fragment = two coalesced global_load_dwordx4. Consequences:
//   - no LDS, no __syncthreads, no DMA drain, no bank conflicts;
//   - 8 independent 64x64-tile wave-streams per CU (one wave per tile,
//     4 per 256-thr block, never synced), ping-pong register buffers,
//     compiler-scheduled counted vmcnt;
//   - A-reuse via grid order (4 row-tiles/block, col-tiles consecutive);
//     B shared by the block's 4 waves through L1.
// Producers write pack layout directly: cast_pack (x8, wq8), xi_prep8
// (xi8, xit8 - unchanged R10), MODE0/1 epilogues (q8, E8 via bpack_addr on
// the row dim; u32 store at s0=(col0&64)+4*ln covers nt=0..3 = sig order).
// ---------------------------------------------------------------------------

typedef __attribute__((ext_vector_type(4))) int int4v;   // 16 fp8 bytes
typedef __attribute__((ext_vector_type(8))) int int8v;   // 32 fp8 bytes
typedef __attribute__((ext_vector_type(4))) float f32x4; // MFMA C/D 16x16

#define NDIM 1024
#define NPAT 8192
#define NROW 8192

__device__ __forceinline__ unsigned f8pack4(float a, float b, float c, float d) {
  int w = __builtin_amdgcn_cvt_pk_fp8_f32(a, b, 0, false);
  w = __builtin_amdgcn_cvt_pk_fp8_f32(c, d, w, true);
  return (unsigned)w;
}
__device__ __forceinline__ unsigned char f8b(float v) {
  return (unsigned char)(__builtin_amdgcn_cvt_pk_fp8_f32(v, v, 0, false) & 0xff);
}
// sigma: original k-pos c (0..127) -> stored byte index (epilogue pack order)
__device__ __forceinline__ int sig(int c) {
  return (c & 64) | ((c & 15) << 2) | ((c >> 4) & 3);
}
// fragment-native pack address: line (row or col), stored-k-pos s (0..127),
// k-tile kt, k-tiles-per-line nkt -> byte offset. Lane L=(quad*16+ln) of the
// MFMA fragment reads its 32B as two 16B at s = quad*32 + h*16 (+0..15):
//   addr = panel(line>>4, kt) + h*1024 + L*16 + (s&15)
__device__ __forceinline__ long bpack_addr(int line, int s, int kt, int nkt) {
  return (((long)(line >> 4) * nkt + kt) * 2 + ((s >> 4) & 1)) * 1024 +
         ((s >> 5) * 16 + (line & 15)) * 16 + (s & 15);
}

// --------------------------- prep kernels ----------------------------------

// f32 [rows,1024] row-major -> fragment-native pack, plain k-order.
__global__ void cast_pack(const float* __restrict__ in,
                          unsigned char* __restrict__ out, float scale) {
  int i = blockIdx.x * blockDim.x + threadIdx.x;
  int rw = i >> 8, d = (i & 255) * 4;
  float4 v = ((const float4*)in)[i];
  unsigned w = f8pack4(v.x * scale, v.y * scale, v.z * scale, v.w * scale);
  *(unsigned*)(out + bpack_addr(rw, d & 127, d >> 7, NDIM >> 7)) = w;
}

// xi f32 [8192,1024] -> xi8  = B of GEMM2 (line=p, k=d, sigma on d),
//                       xit8 = B of GEMM3 (line=d, k=p, sigma on p),
// both fragment-native packed; colsum[1024] fp32.  (R10-verified.)
__global__ void xi_prep8(const float* __restrict__ xi,
                         unsigned char* __restrict__ xi8,
                         unsigned char* __restrict__ xit8,
                         float* __restrict__ colsum) {
  __shared__ float t[32][33];
  __shared__ float cs[8][32];
  int tx = threadIdx.x, ty = threadIdx.y;
  int d0 = blockIdx.x * 32, p0 = blockIdx.y * 32;
  int d = d0 + tx;
  const int s2 = sig(d & 127), kt2 = d >> 7;
  float psum = 0.f;
#pragma unroll
  for (int j = 0; j < 32; j += 8) {
    int p = p0 + ty + j;
    float v = xi[(long)p * NDIM + d];
    t[ty + j][tx] = v;
    psum += v;
    xi8[bpack_addr(p, s2, kt2, NDIM >> 7)] = f8b(32.f * v);
  }
  cs[ty][tx] = psum;
  __syncthreads();
  if (ty == 0) {
    float s = 0.f;
#pragma unroll
    for (int k = 0; k < 8; ++k) s += cs[k][tx];
    atomicAdd(&colsum[d0 + tx], s);
  }
  int p = p0 + tx;
  const int s3 = sig(p & 127), kt3 = p >> 7;
#pragma unroll
  for (int j = 0; j < 32; j += 8)
    xit8[bpack_addr(d0 + ty + j, s3, kt3, NPAT >> 7)] = f8b(32.f * t[tx][ty + j]);
}

// --------------------------- zero-LDS fp8 GEMM -----------------------------
// acc[m,n] = sum_k A[m,k]*B[n,k]; both operands fragment-native packed.
// One wave owns a 64x64 tile (acc 4x4 f32x4). 256-thr block = 4 independent
// waves: 4 consecutive row-tiles x SAME col-tile (B shared via L1). No
// barriers. Ping-pong register double-buffer over K-tiles of 128B.
// MODE 0: q8 pack store [GEMM1]   MODE 1: F pack + rowsum   MODE 2: f32 out

#define MFMA1(D, AF, BF) \
  D = __builtin_amdgcn_mfma_scale_f32_16x16x128_f8f6f4( \
      AF, BF, D, 0, 0, 0, 0x7f7f7f7f, 0, 0x7f7f7f7f);

#define KBODY(KT, CURA, CURB, NXTA, NXTB)                                   \
  {                                                                         \
    const long o1 = ((KT) + 1 < nkt) ? 2048 : 0;                            \
    _Pragma("unroll") for (int t = 0; t < 4; ++t) {                         \
      int4v alo = *(const int4v*)(pAf[t] + o1);                             \
      int4v ahi = *(const int4v*)(pAf[t] + o1 + 1024);                      \
      NXTA[t] = __builtin_shufflevector(alo, ahi, 0, 1, 2, 3, 4, 5, 6, 7);  \
      int4v blo = *(const int4v*)(pBf[t] + o1);                             \
      int4v bhi = *(const int4v*)(pBf[t] + o1 + 1024);                      \
      NXTB[t] = __builtin_shufflevector(blo, bhi, 0, 1, 2, 3, 4, 5, 6, 7);  \
    }                                                                       \
    __builtin_amdgcn_s_setprio(1);                                          \
    _Pragma("unroll") for (int mt = 0; mt < 4; ++mt)                        \
      _Pragma("unroll") for (int nt = 0; nt < 4; ++nt)                      \
        MFMA1(acc[mt][nt], CURA[mt], CURB[nt])                              \
    __builtin_amdgcn_s_setprio(0);                                          \
    _Pragma("unroll") for (int t = 0; t < 4; ++t) {                         \
      pAf[t] += 2048;                                                       \
      pBf[t] += 2048;                                                       \
    }                                                                       \
  }

template <int MODE>
__launch_bounds__(256, 2)
__global__ void gemm_f8(const unsigned char* __restrict__ Ap,
                        const unsigned char* __restrict__ Bp,
                        void* __restrict__ Cv, int N, int K,
                        const float* __restrict__ beta_ptr,
                        const float* __restrict__ rowsum,
                        const float* __restrict__ colsum,
                        float* __restrict__ rowsum_out) {
  const int tid = threadIdx.x;
  const int wave = tid >> 6;
  const int lane = tid & 63;
  const int quad = lane >> 4, ln = lane & 15;

  // block = 4 consecutive row-tiles x one col-tile; col-tiles consecutive in
  // grid order so same-A groups dispatch together (A-panel L2-hot).
  const int nct = N >> 6;
  const int ct = blockIdx.x % nct;
  const int rt4 = blockIdx.x / nct;
  const long row0 = ((long)rt4 * 4 + wave) * 64;
  const long col0 = (long)ct * 64;
  const int nkt = K >> 7;

  // fragment base pointers (frag t: row/col-tile +t), lane-linear, 16B align
  const unsigned char* pAf[4];
  const unsigned char* pBf[4];
#pragma unroll
  for (int t = 0; t < 4; ++t) {
    pAf[t] = Ap + ((long)((int)(row0 >> 4) + t) * nkt) * 2048 + lane * 16;
    pBf[t] = Bp + ((long)((int)(col0 >> 4) + t) * nkt) * 2048 + lane * 16;
  }

  f32x4 acc[4][4] = {};
  int8v aC[4], bC[4], aN[4], bN[4];

  // prologue: load K-tile 0 into current buffers
#pragma unroll
  for (int t = 0; t < 4; ++t) {
    int4v alo = *(const int4v*)(pAf[t]);
    int4v ahi = *(const int4v*)(pAf[t] + 1024);
    aC[t] = __builtin_shufflevector(alo, ahi, 0, 1, 2, 3, 4, 5, 6, 7);
    int4v blo = *(const int4v*)(pBf[t]);
    int4v bhi = *(const int4v*)(pBf[t] + 1024);
    bC[t] = __builtin_shufflevector(blo, bhi, 0, 1, 2, 3, 4, 5, 6, 7);
  }

  for (int kt = 0; kt < nkt; kt += 2) {  // nkt is 8 or 64: always even
    KBODY(kt, aC, bC, aN, bN)
    KBODY(kt + 1, aN, bN, aC, bC)
  }

  // epilogue. C/D frag: col = ln (within 16-tile), row = quad*4 + r.
  if (MODE == 0 || MODE == 1) {
    // pack u32 store: original col c = col0+16*nt+ln -> stored-k pos
    // s = sig(c) = (col0&64) + 4*ln + nt; u32 at s0 = (col0&64)+4*ln.
    unsigned char* C8 = (unsigned char*)Cv;
    const int s0 = (int)(col0 & 64) + 4 * ln;
    const int kc = (int)(col0 >> 7);
    const int onk = N >> 7;
    if (MODE == 0) {
      const float s = 1.0f / 32.0f;
#pragma unroll
      for (int mt = 0; mt < 4; ++mt)
#pragma unroll
        for (int r = 0; r < 4; ++r) {
          int row = (int)row0 + mt * 16 + quad * 4 + r;
          unsigned w = f8pack4(acc[mt][0][r] * s, acc[mt][1][r] * s,
                               acc[mt][2][r] * s, acc[mt][3][r] * s);
          *(unsigned*)(C8 + bpack_addr(row, s0, kc, onk)) = w;
        }
    } else {
      const float bs = beta_ptr[0] * (1.0f / 32.0f);
#pragma unroll
      for (int mt = 0; mt < 4; ++mt)
#pragma unroll
        for (int r = 0; r < 4; ++r) {
          int row = (int)row0 + mt * 16 + quad * 4 + r;
          float e0 = (__expf(bs * acc[mt][0][r]) - 1.0f) * 32.f;
          float e1 = (__expf(bs * acc[mt][1][r]) - 1.0f) * 32.f;
          float e2 = (__expf(bs * acc[mt][2][r]) - 1.0f) * 32.f;
          float e3 = (__expf(bs * acc[mt][3][r]) - 1.0f) * 32.f;
          *(unsigned*)(C8 + bpack_addr(row, s0, kc, onk)) =
              f8pack4(e0, e1, e2, e3);
          float sm = e0 + e1 + e2 + e3;
          sm += __shfl_xor(sm, 1, 64);
          sm += __shfl_xor(sm, 2, 64);
          sm += __shfl_xor(sm, 4, 64);
          sm += __shfl_xor(sm, 8, 64);
          if (ln == 0) atomicAdd(&rowsum_out[row], sm);
        }
    }
  } else {
    float* C = (float*)Cv;
#pragma unroll
    for (int mt = 0; mt < 4; ++mt)
#pragma unroll
      for (int r = 0; r < 4; ++r) {
        long row = row0 + mt * 16 + quad * 4 + r;
        float inv = 1.0f / (8192.0f + rowsum[row] * (1.0f / 32.0f));
#pragma unroll
        for (int nt = 0; nt < 4; ++nt) {
          long col = col0 + nt * 16 + ln;
          C[row * N + col] =
              (acc[mt][nt][r] * (1.0f / 1024.0f) + colsum[col]) * inv;
        }
      }
  }
}

// --------------------------- launch ----------------------------------------

extern "C" void kernel_launch(void* const* d_in, const int* in_sizes, int n_in,
                              void* d_out, int out_size, void* d_ws,
                              size_t ws_size, hipStream_t stream) {
  const float* x    = (const float*)d_in[0];
  const float* wq   = (const float*)d_in[1];
  const float* xi   = (const float*)d_in[2];
  const float* beta = (const float*)d_in[3];
  float* out = (float*)d_out;

  char* ws = (char*)d_ws;
  const size_t MB = 1024 * 1024;
  unsigned char* x8   = (unsigned char*)(ws);             //  8 MiB (packed)
  unsigned char* wq8  = (unsigned char*)(ws + 8 * MB);    //  1 MiB (packed)
  unsigned char* q8   = (unsigned char*)(ws + 9 * MB);    //  8 MiB (packed)
  unsigned char* xi8  = (unsigned char*)(ws + 17 * MB);   //  8 MiB (packed)
  unsigned char* xit8 = (unsigned char*)(ws + 25 * MB);   //  8 MiB (packed)
  float*         rs   = (float*)(ws + 33 * MB);           // 32 KiB
  float*         csum = (float*)(ws + 33 * MB + 32768);   //  4 KiB
  unsigned char* E8   = (unsigned char*)(ws + 34 * MB);   // 64 MiB (packed)

  hipMemsetAsync(rs, 0, 36864, stream);  // rs + colsum

  cast_pack<<<(NROW * NDIM / 4) / 256, 256, 0, stream>>>(x, x8, 1.0f);
  cast_pack<<<(NDIM * NDIM / 4) / 256, 256, 0, stream>>>(wq, wq8, 32.0f);
  xi_prep8<<<dim3(NDIM / 32, NPAT / 32), dim3(32, 8), 0, stream>>>(
      xi, xi8, xit8, csum);

  // GEMM1: q = x @ wq^T (acc = 32q) -> q8 packed. 512 blocks.
  gemm_f8<0><<<(NROW / 256) * (NDIM / 64), 256, 0, stream>>>(
      x8, wq8, q8, NDIM, NDIM, nullptr, nullptr, nullptr, nullptr);

  // GEMM2: F = 32*(exp(beta*q.xi)-1) -> E8 packed + rowsums. 4096 blocks.
  gemm_f8<1><<<(NROW / 256) * (NPAT / 64), 256, 0, stream>>>(
      q8, xi8, E8, NPAT, NDIM, beta, nullptr, nullptr, rs);

  // GEMM3: out = (colsum + F@xi/32) / (8192 + rowsum/32). 512 blocks.
  gemm_f8<2><<<(NROW / 256) * (NDIM / 64), 256, 0, stream>>>(
      E8, xit8, out, NDIM, NPAT, nullptr, rs, csum, nullptr);
}

// Round 8
// 324.451 us; speedup vs baseline: 1.1710x; 1.1710x over previous
//
#include <hip/hip_runtime.h>

// ---------------------------------------------------------------------------
// HopfieldLayer via 3x MX-fp8 MFMA GEMMs (mfma_scale_f32_16x16x128_f8f6f4,
// uniform scales = 1.0). Softmax folded: GEMM2 stores F = 32*(exp(beta*l)-1)
// in fp8 + fp32 row sums; GEMM3 computes
// out = (colsum + F@xi/32) / (8192 + rowsum/32) with exact fp32 colsum.
// All K-orders carry the sigma permutation (within 128-chunks) consistently
// on both operands -> dot products are perm-invariant. (Validated R10/R11.)
//
// R12: zero-LDS GEMM (R11 structure: one wave owns a 64x64 tile, 4 unsynced
// waves/block, ping-pong register buffers, no barriers) + two targeted fixes
// from R11's post-mortem:
//  FIX 1 (serialization): pack layout now stores each lane's 32B fragment
//    CONTIGUOUSLY: panel offset = lane*32 + (s&31), lane=(s>>5)*16+(line&15).
//    One *(int8v*) load = two adjacent dwordx4, no shufflevector merge movs
//    -> compiler can sink vmcnt waits into the MFMA cluster; ping-pong
//    actually pipelines. (R11 split halves 1024B apart -> merge movs forced
//    a vmcnt drain BEFORE the cluster = no pipeline.)
//  FIX 2 (L3-bound traffic): R11 moved 2.1GB through L3 (A,B panels are 8MB
//    > 4MB per-XCD L2; default order gave XCDs no compact working set;
//    2.1GB/140us = 15 TB/s = the wall). XCD-banded 2D grid: xcd=bid%8
//    (round-robin dispatch); each XCD owns a 4-rt4 row band (A-slab 1MB,
//    L2-resident across its whole sweep) and sweeps ct in 8-wide chunks
//    (concurrent set ~1MB A + 1MB B <= 4MB L2). 2D-compact per XCD, unlike
//    R5's linear-chunk remap (that one put full-B strips per XCD).
// ---------------------------------------------------------------------------

typedef __attribute__((ext_vector_type(8))) int int8v;   // 32 fp8 bytes
typedef __attribute__((ext_vector_type(4))) float f32x4; // MFMA C/D 16x16

#define NDIM 1024
#define NPAT 8192
#define NROW 8192

__device__ __forceinline__ unsigned f8pack4(float a, float b, float c, float d) {
  int w = __builtin_amdgcn_cvt_pk_fp8_f32(a, b, 0, false);
  w = __builtin_amdgcn_cvt_pk_fp8_f32(c, d, w, true);
  return (unsigned)w;
}
__device__ __forceinline__ unsigned char f8b(float v) {
  return (unsigned char)(__builtin_amdgcn_cvt_pk_fp8_f32(v, v, 0, false) & 0xff);
}
// sigma: original k-pos c (0..127) -> stored byte index (epilogue pack order)
__device__ __forceinline__ int sig(int c) {
  return (c & 64) | ((c & 15) << 2) | ((c >> 4) & 3);
}
// fragment-native pack: line (row/col), stored-k-pos s (0..127), k-tile kt.
// Lane L=(s>>5)*16+(line&15) holds bytes [L*32, L*32+32) of the 2KB panel:
//   addr = panel(line>>4, kt)*2048 + ((s>>5)*16 + (line&15))*32 + (s&31)
// -> each MFMA fragment is ONE contiguous 32B per lane (FIX 1).
__device__ __forceinline__ long bpack_addr(int line, int s, int kt, int nkt) {
  return ((long)(line >> 4) * nkt + kt) * 2048 +
         (((s >> 5) << 4) + (line & 15)) * 32 + (s & 31);
}

// --------------------------- prep kernels ----------------------------------

// f32 [rows,1024] row-major -> fragment-native pack, plain k-order (s = d).
__global__ void cast_pack(const float* __restrict__ in,
                          unsigned char* __restrict__ out, float scale) {
  int i = blockIdx.x * blockDim.x + threadIdx.x;
  int rw = i >> 8, d = (i & 255) * 4;
  float4 v = ((const float4*)in)[i];
  unsigned w = f8pack4(v.x * scale, v.y * scale, v.z * scale, v.w * scale);
  *(unsigned*)(out + bpack_addr(rw, d & 127, d >> 7, NDIM >> 7)) = w;
}

// xi f32 [8192,1024] -> xi8  = B of GEMM2 (line=p, k=d, sigma on d),
//                       xit8 = B of GEMM3 (line=d, k=p, sigma on p),
// both fragment-native packed; colsum[1024] fp32.
__global__ void xi_prep8(const float* __restrict__ xi,
                         unsigned char* __restrict__ xi8,
                         unsigned char* __restrict__ xit8,
                         float* __restrict__ colsum) {
  __shared__ float t[32][33];
  __shared__ float cs[8][32];
  int tx = threadIdx.x, ty = threadIdx.y;
  int d0 = blockIdx.x * 32, p0 = blockIdx.y * 32;
  int d = d0 + tx;
  const int s2 = sig(d & 127), kt2 = d >> 7;
  float psum = 0.f;
#pragma unroll
  for (int j = 0; j < 32; j += 8) {
    int p = p0 + ty + j;
    float v = xi[(long)p * NDIM + d];
    t[ty + j][tx] = v;
    psum += v;
    xi8[bpack_addr(p, s2, kt2, NDIM >> 7)] = f8b(32.f * v);
  }
  cs[ty][tx] = psum;
  __syncthreads();
  if (ty == 0) {
    float s = 0.f;
#pragma unroll
    for (int k = 0; k < 8; ++k) s += cs[k][tx];
    atomicAdd(&colsum[d0 + tx], s);
  }
  int p = p0 + tx;
  const int s3 = sig(p & 127), kt3 = p >> 7;
#pragma unroll
  for (int j = 0; j < 32; j += 8)
    xit8[bpack_addr(d0 + ty + j, s3, kt3, NPAT >> 7)] = f8b(32.f * t[tx][ty + j]);
}

// --------------------------- zero-LDS fp8 GEMM -----------------------------
// acc[m,n] = sum_k A[m,k]*B[n,k]; both operands fragment-native packed.
// One wave owns a 64x64 tile (acc 4x4 f32x4). 256-thr block = 4 independent
// waves (4 consecutive row-tiles x same col-tile; B shared via L1), no
// barriers, ping-pong register double-buffer over 128B K-tiles.
// MODE 0: q8 pack store [GEMM1]   MODE 1: F pack + rowsum   MODE 2: f32 out

#define MFMA1(D, AF, BF) \
  D = __builtin_amdgcn_mfma_scale_f32_16x16x128_f8f6f4( \
      AF, BF, D, 0, 0, 0, 0x7f7f7f7f, 0, 0x7f7f7f7f);

#define KBODY(KT, CURA, CURB, NXTA, NXTB)                                   \
  {                                                                         \
    const long o1 = ((KT) + 1 < nkt) ? 2048 : 0;                            \
    _Pragma("unroll") for (int t = 0; t < 4; ++t) {                         \
      NXTA[t] = *(const int8v*)(pAf[t] + o1);                               \
      NXTB[t] = *(const int8v*)(pBf[t] + o1);                               \
    }                                                                       \
    __builtin_amdgcn_s_setprio(1);                                          \
    _Pragma("unroll") for (int mt = 0; mt < 4; ++mt)                        \
      _Pragma("unroll") for (int nt = 0; nt < 4; ++nt)                      \
        MFMA1(acc[mt][nt], CURA[mt], CURB[nt])                              \
    __builtin_amdgcn_s_setprio(0);                                          \
    _Pragma("unroll") for (int t = 0; t < 4; ++t) {                         \
      pAf[t] += 2048;                                                       \
      pBf[t] += 2048;                                                       \
    }                                                                       \
  }

template <int MODE>
__launch_bounds__(256, 2)
__global__ void gemm_f8(const unsigned char* __restrict__ Ap,
                        const unsigned char* __restrict__ Bp,
                        void* __restrict__ Cv, int N, int K,
                        const float* __restrict__ beta_ptr,
                        const float* __restrict__ rowsum,
                        const float* __restrict__ colsum,
                        float* __restrict__ rowsum_out) {
  const int tid = threadIdx.x;
  const int wave = tid >> 6;
  const int lane = tid & 63;
  const int quad = lane >> 4, ln = lane & 15;

  // XCD-banded 2D order (FIX 2). M = 8192 always: nrt4 = 32, band = 4 rt4
  // per XCD. Within a band: ct in chunks of 8, rt4_loc inner, c_outer outer
  // -> concurrent per-XCD set ~1MB A (L2-resident all sweep) + ~1MB B.
  const int xcd = blockIdx.x & 7;
  const int idx = blockIdx.x >> 3;
  const int ct_in = idx & 7;
  const int rt4_loc = (idx >> 3) & 3;
  const int c_outer = idx >> 5;
  const int rt4 = xcd * 4 + rt4_loc;
  const int ct = c_outer * 8 + ct_in;

  const long row0 = ((long)rt4 * 4 + wave) * 64;
  const long col0 = (long)ct * 64;
  const int nkt = K >> 7;

  // fragment base pointers (frag t: row/col-tile +t): ONE 32B load per frag
  const unsigned char* pAf[4];
  const unsigned char* pBf[4];
#pragma unroll
  for (int t = 0; t < 4; ++t) {
    pAf[t] = Ap + ((long)((int)(row0 >> 4) + t) * nkt) * 2048 + lane * 32;
    pBf[t] = Bp + ((long)((int)(col0 >> 4) + t) * nkt) * 2048 + lane * 32;
  }

  f32x4 acc[4][4] = {};
  int8v aC[4], bC[4], aN[4], bN[4];

  // prologue: load K-tile 0
#pragma unroll
  for (int t = 0; t < 4; ++t) {
    aC[t] = *(const int8v*)(pAf[t]);
    bC[t] = *(const int8v*)(pBf[t]);
  }

  for (int kt = 0; kt < nkt; kt += 2) {  // nkt is 8 or 64: always even
    KBODY(kt, aC, bC, aN, bN)
    KBODY(kt + 1, aN, bN, aC, bC)
  }

  // epilogue. C/D frag: col = ln (within 16-tile), row = quad*4 + r.
  if (MODE == 0 || MODE == 1) {
    // pack u32 store: original col c = col0+16*nt+ln -> stored-k pos
    // s = sig(c) = (col0&64) + 4*ln + nt; u32 covers nt=0..3.
    unsigned char* C8 = (unsigned char*)Cv;
    const int s0 = (int)(col0 & 64) + 4 * ln;
    const int kc = (int)(col0 >> 7);
    const int onk = N >> 7;
    if (MODE == 0) {
      const float s = 1.0f / 32.0f;
#pragma unroll
      for (int mt = 0; mt < 4; ++mt)
#pragma unroll
        for (int r = 0; r < 4; ++r) {
          int row = (int)row0 + mt * 16 + quad * 4 + r;
          unsigned w = f8pack4(acc[mt][0][r] * s, acc[mt][1][r] * s,
                               acc[mt][2][r] * s, acc[mt][3][r] * s);
          *(unsigned*)(C8 + bpack_addr(row, s0, kc, onk)) = w;
        }
    } else {
      const float bs = beta_ptr[0] * (1.0f / 32.0f);
#pragma unroll
      for (int mt = 0; mt < 4; ++mt)
#pragma unroll
        for (int r = 0; r < 4; ++r) {
          int row = (int)row0 + mt * 16 + quad * 4 + r;
          float e0 = (__expf(bs * acc[mt][0][r]) - 1.0f) * 32.f;
          float e1 = (__expf(bs * acc[mt][1][r]) - 1.0f) * 32.f;
          float e2 = (__expf(bs * acc[mt][2][r]) - 1.0f) * 32.f;
          float e3 = (__expf(bs * acc[mt][3][r]) - 1.0f) * 32.f;
          *(unsigned*)(C8 + bpack_addr(row, s0, kc, onk)) =
              f8pack4(e0, e1, e2, e3);
          float sm = e0 + e1 + e2 + e3;
          sm += __shfl_xor(sm, 1, 64);
          sm += __shfl_xor(sm, 2, 64);
          sm += __shfl_xor(sm, 4, 64);
          sm += __shfl_xor(sm, 8, 64);
          if (ln == 0) atomicAdd(&rowsum_out[row], sm);
        }
    }
  } else {
    float* C = (float*)Cv;
#pragma unroll
    for (int mt = 0; mt < 4; ++mt)
#pragma unroll
      for (int r = 0; r < 4; ++r) {
        long row = row0 + mt * 16 + quad * 4 + r;
        float inv = 1.0f / (8192.0f + rowsum[row] * (1.0f / 32.0f));
#pragma unroll
        for (int nt = 0; nt < 4; ++nt) {
          long col = col0 + nt * 16 + ln;
          C[row * N + col] =
              (acc[mt][nt][r] * (1.0f / 1024.0f) + colsum[col]) * inv;
        }
      }
  }
}

// --------------------------- launch ----------------------------------------

extern "C" void kernel_launch(void* const* d_in, const int* in_sizes, int n_in,
                              void* d_out, int out_size, void* d_ws,
                              size_t ws_size, hipStream_t stream) {
  const float* x    = (const float*)d_in[0];
  const float* wq   = (const float*)d_in[1];
  const float* xi   = (const float*)d_in[2];
  const float* beta = (const float*)d_in[3];
  float* out = (float*)d_out;

  char* ws = (char*)d_ws;
  const size_t MB = 1024 * 1024;
  unsigned char* x8   = (unsigned char*)(ws);             //  8 MiB (packed)
  unsigned char* wq8  = (unsigned char*)(ws + 8 * MB);    //  1 MiB (packed)
  unsigned char* q8   = (unsigned char*)(ws + 9 * MB);    //  8 MiB (packed)
  unsigned char* xi8  = (unsigned char*)(ws + 17 * MB);   //  8 MiB (packed)
  unsigned char* xit8 = (unsigned char*)(ws + 25 * MB);   //  8 MiB (packed)
  float*         rs   = (float*)(ws + 33 * MB);           // 32 KiB
  float*         csum = (float*)(ws + 33 * MB + 32768);   //  4 KiB
  unsigned char* E8   = (unsigned char*)(ws + 34 * MB);   // 64 MiB (packed)

  hipMemsetAsync(rs, 0, 36864, stream);  // rs + colsum

  cast_pack<<<(NROW * NDIM / 4) / 256, 256, 0, stream>>>(x, x8, 1.0f);
  cast_pack<<<(NDIM * NDIM / 4) / 256, 256, 0, stream>>>(wq, wq8, 32.0f);
  xi_prep8<<<dim3(NDIM / 32, NPAT / 32), dim3(32, 8), 0, stream>>>(
      xi, xi8, xit8, csum);

  // GEMM1: q = x @ wq^T (acc = 32q) -> q8 packed. 512 blocks.
  gemm_f8<0><<<(NROW / 256) * (NDIM / 64), 256, 0, stream>>>(
      x8, wq8, q8, NDIM, NDIM, nullptr, nullptr, nullptr, nullptr);

  // GEMM2: F = 32*(exp(beta*q.xi)-1) -> E8 packed + rowsums. 4096 blocks.
  gemm_f8<1><<<(NROW / 256) * (NPAT / 64), 256, 0, stream>>>(
      q8, xi8, E8, NPAT, NDIM, beta, nullptr, nullptr, rs);

  // GEMM3: out = (colsum + F@xi/32) / (8192 + rowsum/32). 512 blocks.
  gemm_f8<2><<<(NROW / 256) * (NDIM / 64), 256, 0, stream>>>(
      E8, xit8, out, NDIM, NPAT, nullptr, rs, csum, nullptr);
}

// Round 9
// 323.506 us; speedup vs baseline: 1.1744x; 1.0029x over previous
//
#include <hip/hip_runtime.h>

// ---------------------------------------------------------------------------
// HopfieldLayer via 3x MX-fp8 MFMA GEMMs (mfma_scale_f32_16x16x128_f8f6f4,
// uniform scales = 1.0). Softmax folded: GEMM2 stores F = 32*(exp(beta*l)-1)
// in fp8 + fp32 row sums; GEMM3 computes
// out = (colsum + F@xi/32) / (8192 + rowsum/32) with exact fp32 colsum.
// All K-orders carry the sigma permutation (within 128-chunks) consistently
// on both operands -> dot products are perm-invariant. (Validated R10-R12.)
//
// R13: R12 (zero-LDS, contiguous-fragment pack, XCD-banded grid; best total
// 324us) + ONE fix. R12's VGPR_Count=108 proved the register ping-pong was
// DEAD: 16 live fragments need 128 VGPRs; the scheduler legally sank the
// NXT loads below the MFMA cluster (no data dep), collapsing to
// load -> vmcnt(0) -> compute (serial: ~700cy latency + 552cy MFMA ~= the
// measured 2194cy/block-iter at 2 waves/SIMD; MfmaUtil 553/2194 = 25%).
//   FIX: __builtin_amdgcn_sched_barrier(0) immediately after each unrolled
//   iter's prefetch-load block. Loads can't sink; both buffers stay live
//   (VGPR ~220, still 2-waves/SIMD quartile, no spill); compiler's
//   auto-waitcnt before CUR use becomes counted vmcnt(16), not a drain.
//   Pointer bumps moved next to the loads so next-iter addresses are ready.
// Falsifiers: VGPR stays ~110 -> pin failed (go inline-asm loads);
// WRITE >110MB -> spill (shrink tile); VGPR up but dur 117 -> latency >
// one cluster (go 2-deep A prefetch).
// ---------------------------------------------------------------------------

typedef __attribute__((ext_vector_type(8))) int int8v;   // 32 fp8 bytes
typedef __attribute__((ext_vector_type(4))) float f32x4; // MFMA C/D 16x16

#define NDIM 1024
#define NPAT 8192
#define NROW 8192

__device__ __forceinline__ unsigned f8pack4(float a, float b, float c, float d) {
  int w = __builtin_amdgcn_cvt_pk_fp8_f32(a, b, 0, false);
  w = __builtin_amdgcn_cvt_pk_fp8_f32(c, d, w, true);
  return (unsigned)w;
}
__device__ __forceinline__ unsigned char f8b(float v) {
  return (unsigned char)(__builtin_amdgcn_cvt_pk_fp8_f32(v, v, 0, false) & 0xff);
}
// sigma: original k-pos c (0..127) -> stored byte index (epilogue pack order)
__device__ __forceinline__ int sig(int c) {
  return (c & 64) | ((c & 15) << 2) | ((c >> 4) & 3);
}
// fragment-native pack: line (row/col), stored-k-pos s (0..127), k-tile kt.
// Lane L=(s>>5)*16+(line&15) holds bytes [L*32, L*32+32) of the 2KB panel:
//   addr = panel(line>>4, kt)*2048 + ((s>>5)*16 + (line&15))*32 + (s&31)
// -> each MFMA fragment is ONE contiguous 32B per lane.
__device__ __forceinline__ long bpack_addr(int line, int s, int kt, int nkt) {
  return ((long)(line >> 4) * nkt + kt) * 2048 +
         (((s >> 5) << 4) + (line & 15)) * 32 + (s & 31);
}

// --------------------------- prep kernels ----------------------------------

// f32 [rows,1024] row-major -> fragment-native pack, plain k-order (s = d).
__global__ void cast_pack(const float* __restrict__ in,
                          unsigned char* __restrict__ out, float scale) {
  int i = blockIdx.x * blockDim.x + threadIdx.x;
  int rw = i >> 8, d = (i & 255) * 4;
  float4 v = ((const float4*)in)[i];
  unsigned w = f8pack4(v.x * scale, v.y * scale, v.z * scale, v.w * scale);
  *(unsigned*)(out + bpack_addr(rw, d & 127, d >> 7, NDIM >> 7)) = w;
}

// xi f32 [8192,1024] -> xi8  = B of GEMM2 (line=p, k=d, sigma on d),
//                       xit8 = B of GEMM3 (line=d, k=p, sigma on p),
// both fragment-native packed; colsum[1024] fp32.
__global__ void xi_prep8(const float* __restrict__ xi,
                         unsigned char* __restrict__ xi8,
                         unsigned char* __restrict__ xit8,
                         float* __restrict__ colsum) {
  __shared__ float t[32][33];
  __shared__ float cs[8][32];
  int tx = threadIdx.x, ty = threadIdx.y;
  int d0 = blockIdx.x * 32, p0 = blockIdx.y * 32;
  int d = d0 + tx;
  const int s2 = sig(d & 127), kt2 = d >> 7;
  float psum = 0.f;
#pragma unroll
  for (int j = 0; j < 32; j += 8) {
    int p = p0 + ty + j;
    float v = xi[(long)p * NDIM + d];
    t[ty + j][tx] = v;
    psum += v;
    xi8[bpack_addr(p, s2, kt2, NDIM >> 7)] = f8b(32.f * v);
  }
  cs[ty][tx] = psum;
  __syncthreads();
  if (ty == 0) {
    float s = 0.f;
#pragma unroll
    for (int k = 0; k < 8; ++k) s += cs[k][tx];
    atomicAdd(&colsum[d0 + tx], s);
  }
  int p = p0 + tx;
  const int s3 = sig(p & 127), kt3 = p >> 7;
#pragma unroll
  for (int j = 0; j < 32; j += 8)
    xit8[bpack_addr(d0 + ty + j, s3, kt3, NPAT >> 7)] = f8b(32.f * t[tx][ty + j]);
}

// --------------------------- zero-LDS fp8 GEMM -----------------------------
// acc[m,n] = sum_k A[m,k]*B[n,k]; both operands fragment-native packed.
// One wave owns a 64x64 tile (acc 4x4 f32x4). 256-thr block = 4 independent
// waves (4 consecutive row-tiles x same col-tile; B shared via L1), no
// barriers, ping-pong register double-buffer over 128B K-tiles.
// MODE 0: q8 pack store [GEMM1]   MODE 1: F pack + rowsum   MODE 2: f32 out

#define MFMA1(D, AF, BF) \
  D = __builtin_amdgcn_mfma_scale_f32_16x16x128_f8f6f4( \
      AF, BF, D, 0, 0, 0, 0x7f7f7f7f, 0, 0x7f7f7f7f);

#define KBODY(KT, CURA, CURB, NXTA, NXTB)                                   \
  {                                                                         \
    const long o1 = ((KT) + 1 < nkt) ? 2048 : 0;                            \
    _Pragma("unroll") for (int t = 0; t < 4; ++t) {                         \
      NXTA[t] = *(const int8v*)(pAf[t] + o1);                               \
      NXTB[t] = *(const int8v*)(pBf[t] + o1);                               \
      pAf[t] += 2048;                                                       \
      pBf[t] += 2048;                                                       \
    }                                                                       \
    __builtin_amdgcn_sched_barrier(0); /* pin: loads stay above cluster */  \
    __builtin_amdgcn_s_setprio(1);                                          \
    _Pragma("unroll") for (int mt = 0; mt < 4; ++mt)                        \
      _Pragma("unroll") for (int nt = 0; nt < 4; ++nt)                      \
        MFMA1(acc[mt][nt], CURA[mt], CURB[nt])                              \
    __builtin_amdgcn_s_setprio(0);                                          \
  }

template <int MODE>
__launch_bounds__(256, 2)
__global__ void gemm_f8(const unsigned char* __restrict__ Ap,
                        const unsigned char* __restrict__ Bp,
                        void* __restrict__ Cv, int N, int K,
                        const float* __restrict__ beta_ptr,
                        const float* __restrict__ rowsum,
                        const float* __restrict__ colsum,
                        float* __restrict__ rowsum_out) {
  const int tid = threadIdx.x;
  const int wave = tid >> 6;
  const int lane = tid & 63;
  const int quad = lane >> 4, ln = lane & 15;

  // XCD-banded 2D order. M = 8192 always: nrt4 = 32, band = 4 rt4 per XCD.
  // Within a band: ct in chunks of 8, rt4_loc inner, c_outer outer ->
  // concurrent per-XCD set ~1MB A (L2-resident all sweep) + ~1MB B.
  const int xcd = blockIdx.x & 7;
  const int idx = blockIdx.x >> 3;
  const int ct_in = idx & 7;
  const int rt4_loc = (idx >> 3) & 3;
  const int c_outer = idx >> 5;
  const int rt4 = xcd * 4 + rt4_loc;
  const int ct = c_outer * 8 + ct_in;

  const long row0 = ((long)rt4 * 4 + wave) * 64;
  const long col0 = (long)ct * 64;
  const int nkt = K >> 7;

  // fragment base pointers (frag t: row/col-tile +t): ONE 32B load per frag
  const unsigned char* pAf[4];
  const unsigned char* pBf[4];
#pragma unroll
  for (int t = 0; t < 4; ++t) {
    pAf[t] = Ap + ((long)((int)(row0 >> 4) + t) * nkt) * 2048 + lane * 32;
    pBf[t] = Bp + ((long)((int)(col0 >> 4) + t) * nkt) * 2048 + lane * 32;
  }

  f32x4 acc[4][4] = {};
  int8v aC[4], bC[4], aN[4], bN[4];

  // prologue: load K-tile 0
#pragma unroll
  for (int t = 0; t < 4; ++t) {
    aC[t] = *(const int8v*)(pAf[t]);
    bC[t] = *(const int8v*)(pBf[t]);
  }

  for (int kt = 0; kt < nkt; kt += 2) {  // nkt is 8 or 64: always even
    KBODY(kt, aC, bC, aN, bN)
    KBODY(kt + 1, aN, bN, aC, bC)
  }

  // epilogue. C/D frag: col = ln (within 16-tile), row = quad*4 + r.
  if (MODE == 0 || MODE == 1) {
    // pack u32 store: original col c = col0+16*nt+ln -> stored-k pos
    // s = sig(c) = (col0&64) + 4*ln + nt; u32 covers nt=0..3.
    unsigned char* C8 = (unsigned char*)Cv;
    const int s0 = (int)(col0 & 64) + 4 * ln;
    const int kc = (int)(col0 >> 7);
    const int onk = N >> 7;
    if (MODE == 0) {
      const float s = 1.0f / 32.0f;
#pragma unroll
      for (int mt = 0; mt < 4; ++mt)
#pragma unroll
        for (int r = 0; r < 4; ++r) {
          int row = (int)row0 + mt * 16 + quad * 4 + r;
          unsigned w = f8pack4(acc[mt][0][r] * s, acc[mt][1][r] * s,
                               acc[mt][2][r] * s, acc[mt][3][r] * s);
          *(unsigned*)(C8 + bpack_addr(row, s0, kc, onk)) = w;
        }
    } else {
      const float bs = beta_ptr[0] * (1.0f / 32.0f);
#pragma unroll
      for (int mt = 0; mt < 4; ++mt)
#pragma unroll
        for (int r = 0; r < 4; ++r) {
          int row = (int)row0 + mt * 16 + quad * 4 + r;
          float e0 = (__expf(bs * acc[mt][0][r]) - 1.0f) * 32.f;
          float e1 = (__expf(bs * acc[mt][1][r]) - 1.0f) * 32.f;
          float e2 = (__expf(bs * acc[mt][2][r]) - 1.0f) * 32.f;
          float e3 = (__expf(bs * acc[mt][3][r]) - 1.0f) * 32.f;
          *(unsigned*)(C8 + bpack_addr(row, s0, kc, onk)) =
              f8pack4(e0, e1, e2, e3);
          float sm = e0 + e1 + e2 + e3;
          sm += __shfl_xor(sm, 1, 64);
          sm += __shfl_xor(sm, 2, 64);
          sm += __shfl_xor(sm, 4, 64);
          sm += __shfl_xor(sm, 8, 64);
          if (ln == 0) atomicAdd(&rowsum_out[row], sm);
        }
    }
  } else {
    float* C = (float*)Cv;
#pragma unroll
    for (int mt = 0; mt < 4; ++mt)
#pragma unroll
      for (int r = 0; r < 4; ++r) {
        long row = row0 + mt * 16 + quad * 4 + r;
        float inv = 1.0f / (8192.0f + rowsum[row] * (1.0f / 32.0f));
#pragma unroll
        for (int nt = 0; nt < 4; ++nt) {
          long col = col0 + nt * 16 + ln;
          C[row * N + col] =
              (acc[mt][nt][r] * (1.0f / 1024.0f) + colsum[col]) * inv;
        }
      }
  }
}

// --------------------------- launch ----------------------------------------

extern "C" void kernel_launch(void* const* d_in, const int* in_sizes, int n_in,
                              void* d_out, int out_size, void* d_ws,
                              size_t ws_size, hipStream_t stream) {
  const float* x    = (const float*)d_in[0];
  const float* wq   = (const float*)d_in[1];
  const float* xi   = (const float*)d_in[2];
  const float* beta = (const float*)d_in[3];
  float* out = (float*)d_out;

  char* ws = (char*)d_ws;
  const size_t MB = 1024 * 1024;
  unsigned char* x8   = (unsigned char*)(ws);             //  8 MiB (packed)
  unsigned char* wq8  = (unsigned char*)(ws + 8 * MB);    //  1 MiB (packed)
  unsigned char* q8   = (unsigned char*)(ws + 9 * MB);    //  8 MiB (packed)
  unsigned char* xi8  = (unsigned char*)(ws + 17 * MB);   //  8 MiB (packed)
  unsigned char* xit8 = (unsigned char*)(ws + 25 * MB);   //  8 MiB (packed)
  float*         rs   = (float*)(ws + 33 * MB);           // 32 KiB
  float*         csum = (float*)(ws + 33 * MB + 32768);   //  4 KiB
  unsigned char* E8   = (unsigned char*)(ws + 34 * MB);   // 64 MiB (packed)

  hipMemsetAsync(rs, 0, 36864, stream);  // rs + colsum

  cast_pack<<<(NROW * NDIM / 4) / 256, 256, 0, stream>>>(x, x8, 1.0f);
  cast_pack<<<(NDIM * NDIM / 4) / 256, 256, 0, stream>>>(wq, wq8, 32.0f);
  xi_prep8<<<dim3(NDIM / 32, NPAT / 32), dim3(32, 8), 0, stream>>>(
      xi, xi8, xit8, csum);

  // GEMM1: q = x @ wq^T (acc = 32q) -> q8 packed. 512 blocks.
  gemm_f8<0><<<(NROW / 256) * (NDIM / 64), 256, 0, stream>>>(
      x8, wq8, q8, NDIM, NDIM, nullptr, nullptr, nullptr, nullptr);

  // GEMM2: F = 32*(exp(beta*q.xi)-1) -> E8 packed + rowsums. 4096 blocks.
  gemm_f8<1><<<(NROW / 256) * (NPAT / 64), 256, 0, stream>>>(
      q8, xi8, E8, NPAT, NDIM, beta, nullptr, nullptr, rs);

  // GEMM3: out = (colsum + F@xi/32) / (8192 + rowsum/32). 512 blocks.
  gemm_f8<2><<<(NROW / 256) * (NDIM / 64), 256, 0, stream>>>(
      E8, xit8, out, NDIM, NPAT, nullptr, rs, csum, nullptr);
}

// Round 10
// 318.111 us; speedup vs baseline: 1.1943x; 1.0170x over previous
//
#include <hip/hip_runtime.h>

// ---------------------------------------------------------------------------
// HopfieldLayer via 3x MX-fp8 MFMA GEMMs (mfma_scale_f32_16x16x128_f8f6f4,
// uniform scales = 1.0). Softmax folded: GEMM2 stores F = 32*(exp(beta*l)-1)
// in fp8 + fp32 row sums; GEMM3 computes
// out = (colsum + F@xi/32) / (8192 + rowsum/32) with exact fp32 colsum.
// All K-orders carry the sigma permutation (within 128-chunks) consistently
// on both operands -> dot products are perm-invariant. (Validated R10-R13.)
//
// R14: R12 (zero-LDS, contiguous-fragment pack, XCD-banded grid; best 323.5)
// MINUS s_setprio / sched_barrier. Rationale: every GEMM variant since R4 --
// LDS-staged or zero-LDS, barriered or not -- lands at the SAME ~2200
// cy/wave-iter, MfmaUtil ~24%, VALU ~27%. The one constant was
// s_setprio(1) around the MFMA cluster. With 2 waves/SIMD running identical
// code, a prio-1 wave monopolizes issue for its ~553cy cluster, starving the
// other wave's LOAD ISSUE -- the only latency cover it has -- then roles
// flip: the waves serialize (period ~ L+553 instead of max(553,(L+553)/2)).
// Guide data says setprio is null-to-NEGATIVE on lockstep GEMM (m190) and
// only pays with role-split scheduling; none of ours has that. R13 also
// proved sched_barrier(0) here is a no-op (identical counters) -> dropped.
// Single-variable change vs R12/R13.
// Falsifier: counters identical again -> limiter is mfma_scale issue
// pattern -> next round switches to 32x32x64_f8f6f4 (8 wider MFMAs/iter).
// ---------------------------------------------------------------------------

typedef __attribute__((ext_vector_type(8))) int int8v;   // 32 fp8 bytes
typedef __attribute__((ext_vector_type(4))) float f32x4; // MFMA C/D 16x16

#define NDIM 1024
#define NPAT 8192
#define NROW 8192

__device__ __forceinline__ unsigned f8pack4(float a, float b, float c, float d) {
  int w = __builtin_amdgcn_cvt_pk_fp8_f32(a, b, 0, false);
  w = __builtin_amdgcn_cvt_pk_fp8_f32(c, d, w, true);
  return (unsigned)w;
}
__device__ __forceinline__ unsigned char f8b(float v) {
  return (unsigned char)(__builtin_amdgcn_cvt_pk_fp8_f32(v, v, 0, false) & 0xff);
}
// sigma: original k-pos c (0..127) -> stored byte index (epilogue pack order)
__device__ __forceinline__ int sig(int c) {
  return (c & 64) | ((c & 15) << 2) | ((c >> 4) & 3);
}
// fragment-native pack: line (row/col), stored-k-pos s (0..127), k-tile kt.
// Lane L=(s>>5)*16+(line&15) holds bytes [L*32, L*32+32) of the 2KB panel:
//   addr = panel(line>>4, kt)*2048 + ((s>>5)*16 + (line&15))*32 + (s&31)
// -> each MFMA fragment is ONE contiguous 32B per lane.
__device__ __forceinline__ long bpack_addr(int line, int s, int kt, int nkt) {
  return ((long)(line >> 4) * nkt + kt) * 2048 +
         (((s >> 5) << 4) + (line & 15)) * 32 + (s & 31);
}

// --------------------------- prep kernels ----------------------------------

// f32 [rows,1024] row-major -> fragment-native pack, plain k-order (s = d).
__global__ void cast_pack(const float* __restrict__ in,
                          unsigned char* __restrict__ out, float scale) {
  int i = blockIdx.x * blockDim.x + threadIdx.x;
  int rw = i >> 8, d = (i & 255) * 4;
  float4 v = ((const float4*)in)[i];
  unsigned w = f8pack4(v.x * scale, v.y * scale, v.z * scale, v.w * scale);
  *(unsigned*)(out + bpack_addr(rw, d & 127, d >> 7, NDIM >> 7)) = w;
}

// xi f32 [8192,1024] -> xi8  = B of GEMM2 (line=p, k=d, sigma on d),
//                       xit8 = B of GEMM3 (line=d, k=p, sigma on p),
// both fragment-native packed; colsum[1024] fp32.
__global__ void xi_prep8(const float* __restrict__ xi,
                         unsigned char* __restrict__ xi8,
                         unsigned char* __restrict__ xit8,
                         float* __restrict__ colsum) {
  __shared__ float t[32][33];
  __shared__ float cs[8][32];
  int tx = threadIdx.x, ty = threadIdx.y;
  int d0 = blockIdx.x * 32, p0 = blockIdx.y * 32;
  int d = d0 + tx;
  const int s2 = sig(d & 127), kt2 = d >> 7;
  float psum = 0.f;
#pragma unroll
  for (int j = 0; j < 32; j += 8) {
    int p = p0 + ty + j;
    float v = xi[(long)p * NDIM + d];
    t[ty + j][tx] = v;
    psum += v;
    xi8[bpack_addr(p, s2, kt2, NDIM >> 7)] = f8b(32.f * v);
  }
  cs[ty][tx] = psum;
  __syncthreads();
  if (ty == 0) {
    float s = 0.f;
#pragma unroll
    for (int k = 0; k < 8; ++k) s += cs[k][tx];
    atomicAdd(&colsum[d0 + tx], s);
  }
  int p = p0 + tx;
  const int s3 = sig(p & 127), kt3 = p >> 7;
#pragma unroll
  for (int j = 0; j < 32; j += 8)
    xit8[bpack_addr(d0 + ty + j, s3, kt3, NPAT >> 7)] = f8b(32.f * t[tx][ty + j]);
}

// --------------------------- zero-LDS fp8 GEMM -----------------------------
// acc[m,n] = sum_k A[m,k]*B[n,k]; both operands fragment-native packed.
// One wave owns a 64x64 tile (acc 4x4 f32x4). 256-thr block = 4 independent
// waves (4 consecutive row-tiles x same col-tile; B shared via L1), no
// barriers, register buffers over 128B K-tiles. NO setprio (see header).
// MODE 0: q8 pack store [GEMM1]   MODE 1: F pack + rowsum   MODE 2: f32 out

#define MFMA1(D, AF, BF) \
  D = __builtin_amdgcn_mfma_scale_f32_16x16x128_f8f6f4( \
      AF, BF, D, 0, 0, 0, 0x7f7f7f7f, 0, 0x7f7f7f7f);

#define KBODY(KT, CURA, CURB, NXTA, NXTB)                                   \
  {                                                                         \
    const long o1 = ((KT) + 1 < nkt) ? 2048 : 0;                            \
    _Pragma("unroll") for (int t = 0; t < 4; ++t) {                         \
      NXTA[t] = *(const int8v*)(pAf[t] + o1);                               \
      NXTB[t] = *(const int8v*)(pBf[t] + o1);                               \
      pAf[t] += 2048;                                                       \
      pBf[t] += 2048;                                                       \
    }                                                                       \
    _Pragma("unroll") for (int mt = 0; mt < 4; ++mt)                        \
      _Pragma("unroll") for (int nt = 0; nt < 4; ++nt)                      \
        MFMA1(acc[mt][nt], CURA[mt], CURB[nt])                              \
  }

template <int MODE>
__launch_bounds__(256, 2)
__global__ void gemm_f8(const unsigned char* __restrict__ Ap,
                        const unsigned char* __restrict__ Bp,
                        void* __restrict__ Cv, int N, int K,
                        const float* __restrict__ beta_ptr,
                        const float* __restrict__ rowsum,
                        const float* __restrict__ colsum,
                        float* __restrict__ rowsum_out) {
  const int tid = threadIdx.x;
  const int wave = tid >> 6;
  const int lane = tid & 63;
  const int quad = lane >> 4, ln = lane & 15;

  // XCD-banded 2D order. M = 8192 always: nrt4 = 32, band = 4 rt4 per XCD.
  // Within a band: ct in chunks of 8, rt4_loc inner, c_outer outer ->
  // concurrent per-XCD set ~1MB A (L2-resident all sweep) + ~1MB B.
  const int xcd = blockIdx.x & 7;
  const int idx = blockIdx.x >> 3;
  const int ct_in = idx & 7;
  const int rt4_loc = (idx >> 3) & 3;
  const int c_outer = idx >> 5;
  const int rt4 = xcd * 4 + rt4_loc;
  const int ct = c_outer * 8 + ct_in;

  const long row0 = ((long)rt4 * 4 + wave) * 64;
  const long col0 = (long)ct * 64;
  const int nkt = K >> 7;

  // fragment base pointers (frag t: row/col-tile +t): ONE 32B load per frag
  const unsigned char* pAf[4];
  const unsigned char* pBf[4];
#pragma unroll
  for (int t = 0; t < 4; ++t) {
    pAf[t] = Ap + ((long)((int)(row0 >> 4) + t) * nkt) * 2048 + lane * 32;
    pBf[t] = Bp + ((long)((int)(col0 >> 4) + t) * nkt) * 2048 + lane * 32;
  }

  f32x4 acc[4][4] = {};
  int8v aC[4], bC[4], aN[4], bN[4];

  // prologue: load K-tile 0
#pragma unroll
  for (int t = 0; t < 4; ++t) {
    aC[t] = *(const int8v*)(pAf[t]);
    bC[t] = *(const int8v*)(pBf[t]);
  }

  for (int kt = 0; kt < nkt; kt += 2) {  // nkt is 8 or 64: always even
    KBODY(kt, aC, bC, aN, bN)
    KBODY(kt + 1, aN, bN, aC, bC)
  }

  // epilogue. C/D frag: col = ln (within 16-tile), row = quad*4 + r.
  if (MODE == 0 || MODE == 1) {
    // pack u32 store: original col c = col0+16*nt+ln -> stored-k pos
    // s = sig(c) = (col0&64) + 4*ln + nt; u32 covers nt=0..3.
    unsigned char* C8 = (unsigned char*)Cv;
    const int s0 = (int)(col0 & 64) + 4 * ln;
    const int kc = (int)(col0 >> 7);
    const int onk = N >> 7;
    if (MODE == 0) {
      const float s = 1.0f / 32.0f;
#pragma unroll
      for (int mt = 0; mt < 4; ++mt)
#pragma unroll
        for (int r = 0; r < 4; ++r) {
          int row = (int)row0 + mt * 16 + quad * 4 + r;
          unsigned w = f8pack4(acc[mt][0][r] * s, acc[mt][1][r] * s,
                               acc[mt][2][r] * s, acc[mt][3][r] * s);
          *(unsigned*)(C8 + bpack_addr(row, s0, kc, onk)) = w;
        }
    } else {
      const float bs = beta_ptr[0] * (1.0f / 32.0f);
#pragma unroll
      for (int mt = 0; mt < 4; ++mt)
#pragma unroll
        for (int r = 0; r < 4; ++r) {
          int row = (int)row0 + mt * 16 + quad * 4 + r;
          float e0 = (__expf(bs * acc[mt][0][r]) - 1.0f) * 32.f;
          float e1 = (__expf(bs * acc[mt][1][r]) - 1.0f) * 32.f;
          float e2 = (__expf(bs * acc[mt][2][r]) - 1.0f) * 32.f;
          float e3 = (__expf(bs * acc[mt][3][r]) - 1.0f) * 32.f;
          *(unsigned*)(C8 + bpack_addr(row, s0, kc, onk)) =
              f8pack4(e0, e1, e2, e3);
          float sm = e0 + e1 + e2 + e3;
          sm += __shfl_xor(sm, 1, 64);
          sm += __shfl_xor(sm, 2, 64);
          sm += __shfl_xor(sm, 4, 64);
          sm += __shfl_xor(sm, 8, 64);
          if (ln == 0) atomicAdd(&rowsum_out[row], sm);
        }
    }
  } else {
    float* C = (float*)Cv;
#pragma unroll
    for (int mt = 0; mt < 4; ++mt)
#pragma unroll
      for (int r = 0; r < 4; ++r) {
        long row = row0 + mt * 16 + quad * 4 + r;
        float inv = 1.0f / (8192.0f + rowsum[row] * (1.0f / 32.0f));
#pragma unroll
        for (int nt = 0; nt < 4; ++nt) {
          long col = col0 + nt * 16 + ln;
          C[row * N + col] =
              (acc[mt][nt][r] * (1.0f / 1024.0f) + colsum[col]) * inv;
        }
      }
  }
}

// --------------------------- launch ----------------------------------------

extern "C" void kernel_launch(void* const* d_in, const int* in_sizes, int n_in,
                              void* d_out, int out_size, void* d_ws,
                              size_t ws_size, hipStream_t stream) {
  const float* x    = (const float*)d_in[0];
  const float* wq   = (const float*)d_in[1];
  const float* xi   = (const float*)d_in[2];
  const float* beta = (const float*)d_in[3];
  float* out = (float*)d_out;

  char* ws = (char*)d_ws;
  const size_t MB = 1024 * 1024;
  unsigned char* x8   = (unsigned char*)(ws);             //  8 MiB (packed)
  unsigned char* wq8  = (unsigned char*)(ws + 8 * MB);    //  1 MiB (packed)
  unsigned char* q8   = (unsigned char*)(ws + 9 * MB);    //  8 MiB (packed)
  unsigned char* xi8  = (unsigned char*)(ws + 17 * MB);   //  8 MiB (packed)
  unsigned char* xit8 = (unsigned char*)(ws + 25 * MB);   //  8 MiB (packed)
  float*         rs   = (float*)(ws + 33 * MB);           // 32 KiB
  float*         csum = (float*)(ws + 33 * MB + 32768);   //  4 KiB
  unsigned char* E8   = (unsigned char*)(ws + 34 * MB);   // 64 MiB (packed)

  hipMemsetAsync(rs, 0, 36864, stream);  // rs + colsum

  cast_pack<<<(NROW * NDIM / 4) / 256, 256, 0, stream>>>(x, x8, 1.0f);
  cast_pack<<<(NDIM * NDIM / 4) / 256, 256, 0, stream>>>(wq, wq8, 32.0f);
  xi_prep8<<<dim3(NDIM / 32, NPAT / 32), dim3(32, 8), 0, stream>>>(
      xi, xi8, xit8, csum);

  // GEMM1: q = x @ wq^T (acc = 32q) -> q8 packed. 512 blocks.
  gemm_f8<0><<<(NROW / 256) * (NDIM / 64), 256, 0, stream>>>(
      x8, wq8, q8, NDIM, NDIM, nullptr, nullptr, nullptr, nullptr);

  // GEMM2: F = 32*(exp(beta*q.xi)-1) -> E8 packed + rowsums. 4096 blocks.
  gemm_f8<1><<<(NROW / 256) * (NPAT / 64), 256, 0, stream>>>(
      q8, xi8, E8, NPAT, NDIM, beta, nullptr, nullptr, rs);

  // GEMM3: out = (colsum + F@xi/32) / (8192 + rowsum/32). 512 blocks.
  gemm_f8<2><<<(NROW / 256) * (NDIM / 64), 256, 0, stream>>>(
      E8, xit8, out, NDIM, NPAT, nullptr, rs, csum, nullptr);
}